// Round 5
// baseline (299.606 us; speedup 1.0000x reference)
//
#include <hip/hip_runtime.h>
#include <hip/hip_bf16.h>

// BinaryLinear: out[131072,256] = x[131072,256] @ (sign(W)*scale)[256,256]^T + bias
// R4: latency-bound at 24% HBM (stage->barrier->compute serialization, VGPR=76).
// Fix: no LDS, no barrier — load MFMA A-frags directly from global (16x128B
// segments per wave-op), cvt f32->bf16 in-reg, full unroll, NT stores for out.

typedef __bf16 bf16_t;
typedef __attribute__((ext_vector_type(8))) __bf16 bf16x8;  // MFMA A/B fragment (4 VGPR)
typedef __attribute__((ext_vector_type(4))) float f32x4;    // MFMA C/D fragment

#define MROWS 131072
#define NDIM 256
#define KDIM 256
#define BM 64

// ---- Kernel 1: wb[o][i] = bf16(sign(W[o][i]))  (+1/-1/0, exact in bf16) ----
__global__ __launch_bounds__(256) void prep_w_kernel(const float* __restrict__ W,
                                                     bf16_t* __restrict__ wb) {
    int idx = blockIdx.x * 256 + threadIdx.x;   // 0 .. 65535
    float w = W[idx];
    float v = (w > 0.0f) ? 1.0f : ((w < 0.0f) ? -1.0f : 0.0f);
    wb[idx] = (bf16_t)v;
}

__device__ inline bf16x8 cvt8(f32x4 lo, f32x4 hi) {
    bf16x8 r;
    r[0] = (bf16_t)lo.x; r[1] = (bf16_t)lo.y; r[2] = (bf16_t)lo.z; r[3] = (bf16_t)lo.w;
    r[4] = (bf16_t)hi.x; r[5] = (bf16_t)hi.y; r[6] = (bf16_t)hi.z; r[7] = (bf16_t)hi.w;
    return r;
}

// ---- Kernel 2: GEMM, no LDS ----
// Block: 256 thr (4 waves), tile 64 rows x 256 cols. Wave w owns cols [w*64, w*64+64).
// A-frag (16x16x32): lane l holds x[row = l&15 (+16*mi)][k = ks*32 + (l>>4)*8 .. +8]
//   -> 8 contiguous f32 = 32 B direct global load; lanes l,l+16,l+32,l+48 share a
//   row -> 16 x 128 B contiguous segments per wave-op (full L2 lines).
// B-frag: wb row  = output col, 8 contiguous bf16 = 16 B (wb is 128 KiB, L2-resident).
__global__ __launch_bounds__(256) void bin_gemm_kernel(
        const float* __restrict__ x,
        const bf16_t* __restrict__ wb,
        const float* __restrict__ scale,
        const float* __restrict__ bias,
        float* __restrict__ out) {
    const int tid   = threadIdx.x;
    const int lane  = tid & 63;
    const int wave  = tid >> 6;
    const int mbase = blockIdx.x * BM;
    const int lrow  = lane & 15;
    const int lk    = lane >> 4;
    const int obase = wave * 64;

    f32x4 acc[4][4] = {};          // 4 m-frags x 4 n-frags of 16x16

    #pragma unroll
    for (int ks = 0; ks < 8; ++ks) {           // K = 8 x 32
        bf16x8 a[4], b[4];
        #pragma unroll
        for (int mi = 0; mi < 4; ++mi) {
            const float* pa = x + (size_t)(mbase + mi * 16 + lrow) * KDIM + ks * 32 + lk * 8;
            f32x4 lo = *reinterpret_cast<const f32x4*>(pa);
            f32x4 hi = *reinterpret_cast<const f32x4*>(pa + 4);
            a[mi] = cvt8(lo, hi);
        }
        #pragma unroll
        for (int ni = 0; ni < 4; ++ni) {
            const bf16_t* pb = wb + (size_t)(obase + ni * 16 + lrow) * KDIM + ks * 32 + lk * 8;
            b[ni] = *reinterpret_cast<const bf16x8*>(pb);
        }
        #pragma unroll
        for (int mi = 0; mi < 4; ++mi)
            #pragma unroll
            for (int ni = 0; ni < 4; ++ni)
                acc[mi][ni] = __builtin_amdgcn_mfma_f32_16x16x32_bf16(
                                  a[mi], b[ni], acc[mi][ni], 0, 0, 0);
    }

    // ---- epilogue: out = acc * scale[col] + bias[col] (f32), NT stores ----
    float sc[4], bi[4];
    #pragma unroll
    for (int ni = 0; ni < 4; ++ni) {
        int col = obase + ni * 16 + lrow;
        sc[ni] = scale[col];
        bi[ni] = bias[col];
    }
    #pragma unroll
    for (int mi = 0; mi < 4; ++mi) {
        #pragma unroll
        for (int ni = 0; ni < 4; ++ni) {
            int col = obase + ni * 16 + lrow;
            #pragma unroll
            for (int r = 0; r < 4; ++r) {
                int row = mbase + mi * 16 + lk * 4 + r;   // C/D: row=(lane>>4)*4+r, col=lane&15
                __builtin_nontemporal_store(acc[mi][ni][r] * sc[ni] + bi[ni],
                                            out + (size_t)row * NDIM + col);
            }
        }
    }
}

extern "C" void kernel_launch(void* const* d_in, const int* in_sizes, int n_in,
                              void* d_out, int out_size, void* d_ws, size_t ws_size,
                              hipStream_t stream) {
    const float* x     = (const float*)d_in[0];
    const float* W     = (const float*)d_in[1];
    const float* scale = (const float*)d_in[2];
    const float* bias  = (const float*)d_in[3];
    float*       out   = (float*)d_out;
    bf16_t*      wb    = (bf16_t*)d_ws;        // 256*256*2 = 128 KiB scratch

    prep_w_kernel<<<NDIM * KDIM / 256, 256, 0, stream>>>(W, wb);
    bin_gemm_kernel<<<MROWS / BM, 256, 0, stream>>>(x, wb, scale, bias, out);
}

// Round 6
// 246.147 us; speedup vs baseline: 1.2172x; 1.2172x over previous
//
#include <hip/hip_runtime.h>
#include <hip/hip_bf16.h>

// BinaryLinear: out[131072,256] = x[131072,256] @ (sign(W)*scale)[256,256]^T + bias
// R5 post-mortem: latency-bound (VGPR=80, serialized loads, 22% HBM).
// R6 structure: block = 512 thr (8 waves), strip = 128 rows. Entire wb (256x256
// bf16 = 128 KiB) staged once into XOR-swizzled LDS; main loop barrier-free.
// Each wave: 16 rows x 256 cols, acc[16] (64 VGPR), explicit 1-ahead x prefetch.
// __launch_bounds__(512,2) -> 256-VGPR budget so loads stay in flight.

typedef __bf16 bf16_t;
typedef __attribute__((ext_vector_type(8))) __bf16 bf16x8;  // MFMA A/B fragment (4 VGPR)
typedef __attribute__((ext_vector_type(4))) float f32x4;    // MFMA C/D fragment

#define MROWS 131072
#define NDIM 256
#define KDIM 256
#define BM 128                 // rows per block (8 waves x 16)

// ---- Kernel 1: wb[o][i] = bf16(sign(W[o][i]))  (+1/-1/0, exact in bf16) ----
__global__ __launch_bounds__(256) void prep_w_kernel(const float* __restrict__ W,
                                                     bf16_t* __restrict__ wb) {
    int idx = blockIdx.x * 256 + threadIdx.x;   // 0 .. 65535
    float w = W[idx];
    float v = (w > 0.0f) ? 1.0f : ((w < 0.0f) ? -1.0f : 0.0f);
    wb[idx] = (bf16_t)v;
}

__device__ inline bf16x8 cvt8(f32x4 lo, f32x4 hi) {
    bf16x8 r;
    r[0] = (bf16_t)lo.x; r[1] = (bf16_t)lo.y; r[2] = (bf16_t)lo.z; r[3] = (bf16_t)lo.w;
    r[4] = (bf16_t)hi.x; r[5] = (bf16_t)hi.y; r[6] = (bf16_t)hi.z; r[7] = (bf16_t)hi.w;
    return r;
}

// ---- Kernel 2: GEMM. wb in LDS (swizzled), x streamed to regs, no loop barriers.
__global__ __launch_bounds__(512, 2) void bin_gemm_kernel(
        const float* __restrict__ x,
        const bf16_t* __restrict__ wb,
        const float* __restrict__ scale,
        const float* __restrict__ bias,
        float* __restrict__ out) {
    // wb_lds[col][k]: row stride 512 B, 16B-slot swizzle byte ^= (col&7)<<4 (T2).
    __shared__ __align__(16) char Blds[NDIM * KDIM * 2];   // 128 KiB

    const int tid = threadIdx.x;

    // ---- one-time stage: 512 thr x 16 pieces x 16 B = 128 KiB, coalesced ----
    #pragma unroll
    for (int p = 0; p < 16; ++p) {
        int idx16 = p * 512 + tid;              // 16B piece, 0..8191
        bf16x8 v = *reinterpret_cast<const bf16x8*>(wb + (size_t)idx16 * 8);
        int col = idx16 >> 5;                   // 32 pieces per 512B row
        int kq  = idx16 & 31;
        int boff = col * 512 + ((kq * 16) ^ ((col & 7) << 4));
        *reinterpret_cast<bf16x8*>(Blds + boff) = v;
    }
    __syncthreads();                            // the only barrier

    const int lane = tid & 63;
    const int wave = tid >> 6;
    const int lrow = lane & 15;                 // A row / B col / C col within frag
    const int lk   = lane >> 4;                 // k-group
    const int r0   = blockIdx.x * BM + wave * 16;
    const float* xrow = x + (size_t)(r0 + lrow) * KDIM + lk * 8;

    f32x4 acc[16] = {};                         // 16 col-tiles, 64 VGPR

    // prefetch ks=0
    f32x4 lo = *reinterpret_cast<const f32x4*>(xrow);
    f32x4 hi = *reinterpret_cast<const f32x4*>(xrow + 4);

    const int sw = (lrow & 7) << 4;
    #pragma unroll
    for (int ks = 0; ks < 8; ++ks) {            // K = 8 x 32
        bf16x8 a = cvt8(lo, hi);
        if (ks < 7) {                           // 1-ahead prefetch of x
            lo = *reinterpret_cast<const f32x4*>(xrow + (ks + 1) * 32);
            hi = *reinterpret_cast<const f32x4*>(xrow + (ks + 1) * 32 + 4);
        }
        int t = lrow * 512 + ((ks * 64 + lk * 16) ^ sw);
        #pragma unroll
        for (int ni = 0; ni < 16; ++ni) {
            bf16x8 b = *reinterpret_cast<const bf16x8*>(Blds + ni * 8192 + t);
            acc[ni] = __builtin_amdgcn_mfma_f32_16x16x32_bf16(a, b, acc[ni], 0, 0, 0);
        }
    }

    // ---- epilogue: out = acc * scale[col] + bias[col] (f32, regular stores) ----
    #pragma unroll
    for (int ni = 0; ni < 16; ++ni) {
        int col = ni * 16 + lrow;
        float sc = scale[col];
        float bi = bias[col];
        #pragma unroll
        for (int r = 0; r < 4; ++r) {
            int row = r0 + lk * 4 + r;          // C/D: row=(lane>>4)*4+r, col=lane&15
            out[(size_t)row * NDIM + col] = acc[ni][r] * sc + bi;
        }
    }
}

extern "C" void kernel_launch(void* const* d_in, const int* in_sizes, int n_in,
                              void* d_out, int out_size, void* d_ws, size_t ws_size,
                              hipStream_t stream) {
    const float* x     = (const float*)d_in[0];
    const float* W     = (const float*)d_in[1];
    const float* scale = (const float*)d_in[2];
    const float* bias  = (const float*)d_in[3];
    float*       out   = (float*)d_out;
    bf16_t*      wb    = (bf16_t*)d_ws;        // 256*256*2 = 128 KiB scratch

    prep_w_kernel<<<NDIM * KDIM / 256, 256, 0, stream>>>(W, wb);
    bin_gemm_kernel<<<MROWS / BM, 512, 0, stream>>>(x, wb, scale, bias, out);
}